// Round 8
// baseline (163.318 us; speedup 1.0000x reference)
//
#include <hip/hip_runtime.h>
#include <hip/hip_bf16.h>

// Segment-mean over N=2,000,000 sorted nodes -> G=16384 graphs, then linear.
// x: [N,64] f32, segment_ids: [N] int32 (sorted), weight: [128,64] f32,
// bias: [128] f32, out: [G,128] f32.  HBM-bound: ~520 MB read -> ~84 us floor.
//
// R8 = R3's proven fused kernel with the LDS removed:
//   - 128-thread blocks (2 waves, 1 graph/wave), NO LDS, NO barrier ->
//     16 WG/CU x 2 waves = 32 waves/CU, retire granularity max-of-2 (~5%)
//     instead of R3's 512-thr/33KB-LDS max-of-8 (~13%).
//   - Epilogue reads W rows l, l+64 straight from global: W = 32 KB = L1-sized,
//     all-hit after warmup; mean broadcast via compile-time-lane __shfl.
//   - Hot loop/search/butterfly byte-identical to R3 (R4-R7 lesson: never
//     touch the streamer).  Single dispatch, no workspace.

#define IN_CH 64
#define OUT_CH 128
#define TBLK 128             // 2 waves per block, 1 graph per wave

typedef float f32x4 __attribute__((ext_vector_type(4)));

__device__ __forceinline__ f32x4 ntload(const float* p) {
    return __builtin_nontemporal_load(reinterpret_cast<const f32x4*>(p));
}

// Branch-free stream of rows [s0,s1); afterwards every lane holds the full
// segment sum of its channel quad [cq, cq+3].
__device__ __forceinline__ void stream_seg(const float* __restrict__ x,
                                           int s0, int s1, int rs, int cq,
                                           float& sx, float& sy,
                                           float& sz, float& sw) {
    float4 a0 = make_float4(0.f, 0.f, 0.f, 0.f);
    float4 a1 = make_float4(0.f, 0.f, 0.f, 0.f);
    int r = s0;
    for (; r + 8 <= s1; r += 8) {
        const f32x4 v0 = ntload(x + (size_t)(r + rs)     * IN_CH + cq);
        const f32x4 v1 = ntload(x + (size_t)(r + 4 + rs) * IN_CH + cq);
        a0.x += v0.x; a0.y += v0.y; a0.z += v0.z; a0.w += v0.w;
        a1.x += v1.x; a1.y += v1.y; a1.z += v1.z; a1.w += v1.w;
    }
    if (r + 4 <= s1) {
        const f32x4 v = ntload(x + (size_t)(r + rs) * IN_CH + cq);
        a0.x += v.x; a0.y += v.y; a0.z += v.z; a0.w += v.w;
        r += 4;
    }
    if (r + rs < s1) {
        const f32x4 v = ntload(x + (size_t)(r + rs) * IN_CH + cq);
        a1.x += v.x; a1.y += v.y; a1.z += v.z; a1.w += v.w;
    }
    sx = a0.x + a1.x; sy = a0.y + a1.y;
    sz = a0.z + a1.z; sw = a0.w + a1.w;
    sx += __shfl_xor(sx, 16); sy += __shfl_xor(sy, 16);
    sz += __shfl_xor(sz, 16); sw += __shfl_xor(sw, 16);
    sx += __shfl_xor(sx, 32); sy += __shfl_xor(sy, 32);
    sz += __shfl_xor(sz, 32); sw += __shfl_xor(sw, 32);
}

__global__ __launch_bounds__(TBLK) void fused_nolds_kernel(
        const float* __restrict__ x, const int* __restrict__ ids,
        const float* __restrict__ W, const float* __restrict__ bias,
        float* __restrict__ out, int N, int G) {
    const int t  = threadIdx.x;
    const int wv = t >> 6;        // wave 0..1
    const int l  = t & 63;
    const int g  = blockIdx.x * (TBLK / 64) + wv;
    if (g >= G) return;

    // ---- windowed binary search (identical to R3): lanes 0/1 find
    // lower_bound(g), lower_bound(g+1); validated +-4096 window with
    // full-range fallback -> correct for any sorted input.
    const int tgt = g + (l & 1);
    int lo = 0, hi = N;
    {
        const int guess = (int)(((long long)tgt * (long long)N) / (long long)G);
        int wlo = guess - 4096; if (wlo < 0) wlo = 0;
        int whi = guess + 4096; if (whi > N) whi = N;
        const bool ok_lo = (wlo == 0) || (ids[wlo - 1] < tgt);
        const bool ok_hi = (whi == N) || (ids[whi] >= tgt);
        if (ok_lo && ok_hi) { lo = wlo; hi = whi; }
        while (lo < hi) {
            const int mid = (lo + hi) >> 1;
            if (ids[mid] < tgt) lo = mid + 1; else hi = mid;
        }
    }
    const int s0 = __shfl(lo, 0);
    const int s1 = __shfl(lo, 1);

    const int rs = l >> 4;              // row stream 0..3
    const int cq = (l & 15) << 2;       // channel quad base

    // ---- stream + reduce (proven)
    float sx, sy, sz, sw;
    stream_seg(x, s0, s1, rs, cq, sx, sy, sz, sw);
    const float cnt = (float)(s1 - s0);
    const float m0 = sx / cnt, m1 = sy / cnt;
    const float m2 = sz / cnt, m3 = sw / cnt;

    // ---- epilogue: out[g][l] and out[g][l+64] from global W rows l, l+64.
    // W is 32 KB (= L1 size): all-hit after the first blocks on each CU.
    // Mean channels c4..c4+3 live in lane (c4>>2) components 0..3.
    const float* w0 = W + (size_t)l        * IN_CH;
    const float* w1 = W + (size_t)(l + 64) * IN_CH;
    float o0 = bias[l];
    float o1 = bias[l + 64];
    #pragma unroll
    for (int c4 = 0; c4 < IN_CH; c4 += 4) {
        const f32x4 wa = *reinterpret_cast<const f32x4*>(w0 + c4);
        const f32x4 wb = *reinterpret_cast<const f32x4*>(w1 + c4);
        const int   src = c4 >> 2;
        const float mm0 = __shfl(m0, src);
        const float mm1 = __shfl(m1, src);
        const float mm2 = __shfl(m2, src);
        const float mm3 = __shfl(m3, src);
        o0 = fmaf(wa.x, mm0, o0); o0 = fmaf(wa.y, mm1, o0);
        o0 = fmaf(wa.z, mm2, o0); o0 = fmaf(wa.w, mm3, o0);
        o1 = fmaf(wb.x, mm0, o1); o1 = fmaf(wb.y, mm1, o1);
        o1 = fmaf(wb.z, mm2, o1); o1 = fmaf(wb.w, mm3, o1);
    }
    out[(size_t)g * OUT_CH + l]      = o0;
    out[(size_t)g * OUT_CH + l + 64] = o1;
}

extern "C" void kernel_launch(void* const* d_in, const int* in_sizes, int n_in,
                              void* d_out, int out_size, void* d_ws, size_t ws_size,
                              hipStream_t stream) {
    const float* x    = (const float*)d_in[0];
    const int*   ids  = (const int*)d_in[1];
    const float* W    = (const float*)d_in[2];
    const float* bias = (const float*)d_in[3];
    float* out = (float*)d_out;

    const int N = in_sizes[1];             // 2,000,000
    const int G = out_size / OUT_CH;       // 16384

    const int blocks = (G + (TBLK / 64) - 1) / (TBLK / 64);   // 8192
    fused_nolds_kernel<<<blocks, TBLK, 0, stream>>>(x, ids, W, bias, out, N, G);
}

// Round 9
// 132.243 us; speedup vs baseline: 1.2350x; 1.2350x over previous
//
#include <hip/hip_runtime.h>
#include <hip/hip_bf16.h>

// Segment-mean over N=2,000,000 sorted nodes -> G=16384 graphs, then linear.
// x: [N,64] f32, segment_ids: [N] int32 (sorted), weight: [128,64] f32,
// bias: [128] f32, out: [G,128] f32.  HBM-bound: ~520 MB read -> ~84 us floor.
//
// R9 = R3 (best: 100.3 us) with a single-cohort 2-octet schedule:
//   - 1024 blocks x 512 thr = exactly 4 blocks/CU x 256 CU, all resident.
//   - Wave wv of block b handles graphs g0 = 8b+wv and g1 = g0 + 8192.
//   - ALL FOUR segment boundaries found in ONE wave-parallel windowed binary
//     search (lanes 0..3 carry targets g0, g0+1, g1, g1+1) - same cost as
//     R3's 2-target search, halving search overhead per graph.
//   - Streamer / LDS-W epilogue byte-identical to R3 (R4-R8 lesson: the
//     8-adjacent-graph lockstep block is load-bearing; never touch it).

#define IN_CH 64
#define OUT_CH 128
#define WPB 8                // waves (graphs) per block per octet
#define BLOCK (WPB * 64)     // 512 threads

typedef float f32x4 __attribute__((ext_vector_type(4)));

__device__ __forceinline__ f32x4 ntload(const float* p) {
    return __builtin_nontemporal_load(reinterpret_cast<const f32x4*>(p));
}

// Branch-free stream of rows [s0,s1); afterwards every lane holds the full
// segment sum of its channel quad [cq, cq+3].
__device__ __forceinline__ void stream_seg(const float* __restrict__ x,
                                           int s0, int s1, int rs, int cq,
                                           float& sx, float& sy,
                                           float& sz, float& sw) {
    float4 a0 = make_float4(0.f, 0.f, 0.f, 0.f);
    float4 a1 = make_float4(0.f, 0.f, 0.f, 0.f);
    int r = s0;
    for (; r + 8 <= s1; r += 8) {
        const f32x4 v0 = ntload(x + (size_t)(r + rs)     * IN_CH + cq);
        const f32x4 v1 = ntload(x + (size_t)(r + 4 + rs) * IN_CH + cq);
        a0.x += v0.x; a0.y += v0.y; a0.z += v0.z; a0.w += v0.w;
        a1.x += v1.x; a1.y += v1.y; a1.z += v1.z; a1.w += v1.w;
    }
    if (r + 4 <= s1) {
        const f32x4 v = ntload(x + (size_t)(r + rs) * IN_CH + cq);
        a0.x += v.x; a0.y += v.y; a0.z += v.z; a0.w += v.w;
        r += 4;
    }
    if (r + rs < s1) {
        const f32x4 v = ntload(x + (size_t)(r + rs) * IN_CH + cq);
        a1.x += v.x; a1.y += v.y; a1.z += v.z; a1.w += v.w;
    }
    sx = a0.x + a1.x; sy = a0.y + a1.y;
    sz = a0.z + a1.z; sw = a0.w + a1.w;
    sx += __shfl_xor(sx, 16); sy += __shfl_xor(sy, 16);
    sz += __shfl_xor(sz, 16); sw += __shfl_xor(sw, 16);
    sx += __shfl_xor(sx, 32); sy += __shfl_xor(sy, 32);
    sz += __shfl_xor(sz, 32); sw += __shfl_xor(sw, 32);
}

// Stream one segment, compute mean, apply W@m+b, store out[g].
__device__ __forceinline__ void do_graph(const float* __restrict__ x,
                                         const float* __restrict__ w_lds,
                                         float b0, float b1,
                                         float* __restrict__ out,
                                         int g, int s0, int s1,
                                         int rs, int cq, int l) {
    float sx, sy, sz, sw;
    stream_seg(x, s0, s1, rs, cq, sx, sy, sz, sw);
    const float cnt = (float)(s1 - s0);
    const float m0 = sx / cnt, m1 = sy / cnt;
    const float m2 = sz / cnt, m3 = sw / cnt;

    float o0 = b0, o1 = b1;
    #pragma unroll
    for (int c = 0; c < IN_CH; ++c) {
        float m;
        switch (c & 3) {
            case 0:  m = __shfl(m0, c >> 2); break;
            case 1:  m = __shfl(m1, c >> 2); break;
            case 2:  m = __shfl(m2, c >> 2); break;
            default: m = __shfl(m3, c >> 2); break;
        }
        o0 = fmaf(w_lds[c * 129 + l],      m, o0);
        o1 = fmaf(w_lds[c * 129 + l + 64], m, o1);
    }
    out[(size_t)g * OUT_CH + l]      = o0;
    out[(size_t)g * OUT_CH + l + 64] = o1;
}

__global__ __launch_bounds__(BLOCK) void fused2_kernel(
        const float* __restrict__ x, const int* __restrict__ ids,
        const float* __restrict__ W, const float* __restrict__ bias,
        float* __restrict__ out, int N, int G, int half) {
    // W transposed: w_lds[c*129 + o] = W[o][c]; stride 129 -> writes 2-way
    // (free) and epilogue reads conflict-free.
    __shared__ float w_lds[IN_CH * 129];
    const int t = threadIdx.x;
    for (int i = t; i < OUT_CH * IN_CH; i += BLOCK) {
        const int o = i >> 6, c = i & 63;
        w_lds[c * 129 + o] = W[i];
    }
    __syncthreads();

    const int wv = t >> 6, l = t & 63;
    const int g0 = blockIdx.x * WPB + wv;      // first octet graph
    const int g1 = g0 + half;                  // second octet graph
    if (g0 >= G) return;

    // ---- ONE wave-parallel windowed binary search for all 4 boundaries.
    // Lane 0: g0, lane 1: g0+1, lane 2: g1, lane >=3: g1+1 (clamped to G).
    int tgt = (l == 0) ? g0 : (l == 1) ? (g0 + 1) : (l == 2) ? g1 : (g1 + 1);
    if (tgt > G) tgt = G;
    int lo = 0, hi = N;
    {
        const int guess = (int)(((long long)tgt * (long long)N) / (long long)G);
        int wlo = guess - 4096; if (wlo < 0) wlo = 0;
        int whi = guess + 4096; if (whi > N) whi = N;
        if (wlo > N) wlo = N;
        const bool ok_lo = (wlo == 0) || (ids[wlo - 1] < tgt);
        const bool ok_hi = (whi == N) || (ids[whi] >= tgt);
        if (ok_lo && ok_hi) { lo = wlo; hi = whi; }
        while (lo < hi) {
            const int mid = (lo + hi) >> 1;
            if (ids[mid] < tgt) lo = mid + 1; else hi = mid;
        }
    }
    const int s0a = __shfl(lo, 0);
    const int s1a = __shfl(lo, 1);
    const int s0b = __shfl(lo, 2);
    const int s1b = __shfl(lo, 3);

    const int rs = l >> 4;              // row stream 0..3
    const int cq = (l & 15) << 2;       // channel quad base
    const float b0 = bias[l], b1 = bias[l + 64];

    do_graph(x, w_lds, b0, b1, out, g0, s0a, s1a, rs, cq, l);
    if (g1 < G)
        do_graph(x, w_lds, b0, b1, out, g1, s0b, s1b, rs, cq, l);
}

extern "C" void kernel_launch(void* const* d_in, const int* in_sizes, int n_in,
                              void* d_out, int out_size, void* d_ws, size_t ws_size,
                              hipStream_t stream) {
    const float* x    = (const float*)d_in[0];
    const int*   ids  = (const int*)d_in[1];
    const float* W    = (const float*)d_in[2];
    const float* bias = (const float*)d_in[3];
    float* out = (float*)d_out;

    const int N = in_sizes[1];             // 2,000,000
    const int G = out_size / OUT_CH;       // 16384

    // 2 octets per block: nb blocks cover 2*WPB*nb >= G graphs.
    const int nb   = (G + 2 * WPB - 1) / (2 * WPB);   // 1024
    const int half = nb * WPB;                        // 8192
    fused2_kernel<<<nb, BLOCK, 0, stream>>>(x, ids, W, bias, out, N, G, half);
}

// Round 10
// 100.844 us; speedup vs baseline: 1.6195x; 1.3114x over previous
//
#include <hip/hip_runtime.h>
#include <hip/hip_bf16.h>

// Problem: segment-mean over N=2,000,000 sorted nodes -> G=16384 graphs, then linear.
// x: [N,64] f32, segment_ids: [N] int32 (sorted), weight: [128,64] f32, bias: [128] f32.
// out: [G,128] f32.  HBM-bound: ~520 MB read + 8 MB write -> ~84 us floor.
//
// FINAL (= R3, best of 10 rounds at 100.3 us, ~82% of achievable read BW):
// single fused kernel; each wave owns one graph, finds its row range via a
// windowed binary search on the sorted ids, streams it branch-free with
// nontemporal float4 loads, reduces via shfl butterfly, applies the linear
// layer from an LDS-resident transposed W tile.
//
// Falsified alternatives (kept as institutional memory):
//  R4 in-stream id checks     124.4 us (id loads serialize the stream)
//  R5 split + min-waves bound 119.0 us (spills + extra dispatch)
//  R6 persistent work-steal   240.5 us (reg bloat + scattered streams)
//  R7 equal-rows + atomics    133.7 us (flush overhead > balance gain)
//  R8 LDS-free 128-thr blocks 163.3 us (lost 8-adjacent-graph locality)
//  R9 2-octet schedule        132.2 us (split stream regions per wave)

#define IN_CH 64
#define OUT_CH 128
#define WPB 8               // waves (= graphs) per block
#define BLOCK (WPB * 64)    // 512 threads

typedef float f32x4 __attribute__((ext_vector_type(4)));

__global__ __launch_bounds__(BLOCK) void fused_pool_linear_kernel(
        const float* __restrict__ x, const int* __restrict__ ids,
        const float* __restrict__ W, const float* __restrict__ bias,
        float* __restrict__ out, int N, int G) {
    // W transposed: w_lds[c*129 + o] = W[o][c]; stride 129 -> conflict-free.
    __shared__ float w_lds[IN_CH * 129];

    const int t  = threadIdx.x;
    const int wv = t >> 6;        // wave in block 0..7
    const int l  = t & 63;        // lane
    const int g  = blockIdx.x * WPB + wv;

    // ---- Per-wave range search: lower_bound(ids, g) and lower_bound(ids, g+1).
    // Even lanes search target g, odd lanes g+1. ids are ~uniform, so
    // lower_bound(tgt) ~= tgt*N/G; use a +-4096 window (>5 sigma), validated,
    // with full-range fallback -> correct for ANY sorted input.
    int s0 = 0, s1 = 0;
    if (g < G) {
        const int target = g + (l & 1);
        int lo = 0, hi = N;
        const int guess = (int)(((long long)target * (long long)N) / (long long)G);
        int wlo = guess - 4096; if (wlo < 0) wlo = 0;
        int whi = guess + 4096; if (whi > N) whi = N;
        const bool ok_lo = (wlo == 0) || (ids[wlo - 1] < target);
        const bool ok_hi = (whi == N) || (ids[whi] >= target);
        if (ok_lo && ok_hi) { lo = wlo; hi = whi; }
        while (lo < hi) {
            const int mid = (lo + hi) >> 1;
            if (ids[mid] < target) lo = mid + 1; else hi = mid;
        }
        s0 = __shfl(lo, 0);
        s1 = __shfl(lo, 1);
    }

    // ---- Stage W into LDS (independent loads, overlap the search chains).
    for (int i = t; i < OUT_CH * IN_CH; i += BLOCK) {
        const int o = i >> 6;     // 0..127
        const int c = i & 63;     // 0..63
        w_lds[c * 129 + o] = W[i];
    }
    __syncthreads();              // only barrier; all threads reach it

    if (g >= G) return;

    const int rs = l >> 4;              // row stream 0..3
    const int cq = (l & 15) << 2;       // channel quad base

    // ---- Stream the segment: 8 rows / iter, two 1 KiB wave-loads in flight.
    // Nontemporal: x is read-once (512 MB) - keep it out of L2/L3 so the ids
    // stay cached for later blocks' searches.
    float4 a0 = make_float4(0.f, 0.f, 0.f, 0.f);
    float4 a1 = make_float4(0.f, 0.f, 0.f, 0.f);
    int r = s0;
    for (; r + 8 <= s1; r += 8) {
        const f32x4 v0 = __builtin_nontemporal_load(
            reinterpret_cast<const f32x4*>(x + (size_t)(r + rs) * IN_CH + cq));
        const f32x4 v1 = __builtin_nontemporal_load(
            reinterpret_cast<const f32x4*>(x + (size_t)(r + 4 + rs) * IN_CH + cq));
        a0.x += v0.x; a0.y += v0.y; a0.z += v0.z; a0.w += v0.w;
        a1.x += v1.x; a1.y += v1.y; a1.z += v1.z; a1.w += v1.w;
    }
    if (r + 4 <= s1) {
        const f32x4 v = __builtin_nontemporal_load(
            reinterpret_cast<const f32x4*>(x + (size_t)(r + rs) * IN_CH + cq));
        a0.x += v.x; a0.y += v.y; a0.z += v.z; a0.w += v.w;
        r += 4;
    }
    if (r + rs < s1) {
        const f32x4 v = __builtin_nontemporal_load(
            reinterpret_cast<const f32x4*>(x + (size_t)(r + rs) * IN_CH + cq));
        a1.x += v.x; a1.y += v.y; a1.z += v.z; a1.w += v.w;
    }

    float sx = a0.x + a1.x;
    float sy = a0.y + a1.y;
    float sz = a0.z + a1.z;
    float sw = a0.w + a1.w;

    // Butterfly over the 4 row streams: every lane ends with the full segment
    // sum for its channel quad [cq, cq+3].
    sx += __shfl_xor(sx, 16); sy += __shfl_xor(sy, 16);
    sz += __shfl_xor(sz, 16); sw += __shfl_xor(sw, 16);
    sx += __shfl_xor(sx, 32); sy += __shfl_xor(sy, 32);
    sz += __shfl_xor(sz, 32); sw += __shfl_xor(sw, 32);

    const float cnt = (float)(s1 - s0);
    const float m0 = sx / cnt;
    const float m1 = sy / cnt;
    const float m2 = sz / cnt;
    const float m3 = sw / cnt;

    // ---- Epilogue: out[g][l], out[g][l+64]. Mean channel c lives in lane
    // (c>>2), component (c&3); compile-time-lane __shfl -> v_readlane.
    float o0 = bias[l];
    float o1 = bias[l + 64];
    #pragma unroll
    for (int c = 0; c < IN_CH; ++c) {
        float m;
        switch (c & 3) {
            case 0:  m = __shfl(m0, c >> 2); break;
            case 1:  m = __shfl(m1, c >> 2); break;
            case 2:  m = __shfl(m2, c >> 2); break;
            default: m = __shfl(m3, c >> 2); break;
        }
        o0 = fmaf(w_lds[c * 129 + l],      m, o0);
        o1 = fmaf(w_lds[c * 129 + l + 64], m, o1);
    }
    out[(size_t)g * OUT_CH + l]      = o0;
    out[(size_t)g * OUT_CH + l + 64] = o1;
}

extern "C" void kernel_launch(void* const* d_in, const int* in_sizes, int n_in,
                              void* d_out, int out_size, void* d_ws, size_t ws_size,
                              hipStream_t stream) {
    const float* x    = (const float*)d_in[0];
    const int*   ids  = (const int*)d_in[1];
    const float* W    = (const float*)d_in[2];
    const float* bias = (const float*)d_in[3];
    float* out = (float*)d_out;

    const int N = in_sizes[1];             // 2,000,000
    const int G = out_size / OUT_CH;       // 16384

    const int blocks = (G + WPB - 1) / WPB;   // 2048
    fused_pool_linear_kernel<<<blocks, BLOCK, 0, stream>>>(
        x, ids, W, bias, out, N, G);
}